// Round 2
// baseline (901.322 us; speedup 1.0000x reference)
//
#include <hip/hip_runtime.h>
#include <hip/hip_bf16.h>

// B=2, L=4096, D=512, H=8, Hd=64, causal MHA, outputs (out, attn) fp32.

typedef __attribute__((ext_vector_type(8))) __bf16 bf16x8;
typedef __attribute__((ext_vector_type(4))) float f32x4;

constexpr int LL = 4096;
constexpr int DD = 512;
constexpr int HH = 8;
constexpr int HD = 64;
constexpr int BB = 2;
constexpr int BL = BB * LL;
constexpr size_t OUT_ELEMS = (size_t)BB * LL * DD;

static __device__ inline bf16x8 cvt8(const float* p) {
    float4 a = *reinterpret_cast<const float4*>(p);
    float4 b = *reinterpret_cast<const float4*>(p + 4);
    bf16x8 r;
    r[0] = (__bf16)a.x; r[1] = (__bf16)a.y; r[2] = (__bf16)a.z; r[3] = (__bf16)a.w;
    r[4] = (__bf16)b.x; r[5] = (__bf16)b.y; r[6] = (__bf16)b.z; r[7] = (__bf16)b.w;
    return r;
}

static __device__ inline float4 up4(unsigned a, unsigned b) {
    float4 r;
    r.x = __uint_as_float(a << 16);
    r.y = __uint_as_float(a & 0xffff0000u);
    r.z = __uint_as_float(b << 16);
    r.w = __uint_as_float(b & 0xffff0000u);
    return r;
}

// ---------------------------------------------------------------------------
// Kernel 1: QKV projection. y = x @ W.T + b, cast bf16.
// z=0 -> Q [B,H,L,64]; z=1 -> K [B,H,L,64]; z=2 -> V^T [B,H,64,L].
// LDS-staged epilogue: all global writes are 16B coalesced (fixes Vt scatter).
// grid (BL/64, 8, 3), block 256.
// ---------------------------------------------------------------------------
__global__ __launch_bounds__(256) void qkv_kernel(
    const float* __restrict__ q_in, const float* __restrict__ k_in,
    const float* __restrict__ v_in,
    const float* __restrict__ Wq, const float* __restrict__ bq,
    const float* __restrict__ Wk, const float* __restrict__ bk,
    const float* __restrict__ Wv, const float* __restrict__ bv,
    __bf16* __restrict__ Qb, __bf16* __restrict__ Kb, __bf16* __restrict__ Vt)
{
    const int z = blockIdx.z;
    const float* x   = (z == 0) ? q_in : (z == 1) ? k_in : v_in;
    const float* W   = (z == 0) ? Wq   : (z == 1) ? Wk   : Wv;
    const float* bia = (z == 0) ? bq   : (z == 1) ? bk   : bv;

    const int wid = threadIdx.x >> 6;
    const int lane = threadIdx.x & 63;
    const int l15 = lane & 15;
    const int lg  = lane >> 4;

    const int r0 = blockIdx.x * 64;
    const int cb = blockIdx.y;               // head index (64-col block)
    const int c0 = cb * 64 + wid * 16;

    f32x4 acc[4] = {};
    for (int k0 = 0; k0 < DD; k0 += 32) {
        bf16x8 bfrag = cvt8(&W[(size_t)(c0 + l15) * DD + k0 + lg * 8]);
#pragma unroll
        for (int mt = 0; mt < 4; ++mt) {
            bf16x8 afrag = cvt8(&x[(size_t)(r0 + mt * 16 + l15) * DD + k0 + lg * 8]);
            acc[mt] = __builtin_amdgcn_mfma_f32_16x16x32_bf16(afrag, bfrag, acc[mt], 0, 0, 0);
        }
    }

    __shared__ __bf16 T[64][72];
    const float bval = bia[c0 + l15];
#pragma unroll
    for (int mt = 0; mt < 4; ++mt)
#pragma unroll
        for (int i = 0; i < 4; ++i) {
            const float val = acc[mt][i] + bval;
            const int row = mt * 16 + lg * 4 + i;     // l within tile
            const int col = wid * 16 + l15;           // hd within head
            if (z == 2) T[col][row] = (__bf16)val;    // transposed for V^T
            else        T[row][col] = (__bf16)val;
        }
    __syncthreads();

    const int tr  = threadIdx.x >> 2;
    const int seg = threadIdx.x & 3;
    uint4 v0 = *reinterpret_cast<const uint4*>(&T[tr][seg * 16]);
    uint4 v1 = *reinterpret_cast<const uint4*>(&T[tr][seg * 16 + 8]);
    const int b  = r0 >> 12;
    const int l0 = r0 & (LL - 1);
    if (z == 2) {
        // T[hd][l]: row tr = hd; contiguous along l
        __bf16* dst = Vt + ((size_t)(b * HH + cb) * HD + tr) * LL + l0 + seg * 16;
        *reinterpret_cast<uint4*>(dst)     = v0;
        *reinterpret_cast<uint4*>(dst + 8) = v1;
    } else {
        __bf16* base = (z == 0) ? Qb : Kb;
        __bf16* dst = base + ((size_t)(b * HH + cb) * LL + l0 + tr) * HD + seg * 16;
        *reinterpret_cast<uint4*>(dst)     = v0;
        *reinterpret_cast<uint4*>(dst + 8) = v1;
    }
}

// ---------------------------------------------------------------------------
// Kernel 2: causal attention, BARRIER-FREE.
// Each wave owns 16 q-rows end-to-end. P transposes through a wave-private
// LDS tile (bf16, +8 pad), ordered only by lgkmcnt — zero __syncthreads.
// Pass 1: row sums (QK + exp). Pass 2: QK recompute, normalized P via
// exp2(fma(s,SC,-log2(l))), attn write (4x dwordx4), PV accumulate.
// grid (16 bh, 64 qb-desc), block 256.
// ---------------------------------------------------------------------------
__global__ __launch_bounds__(256) void attn_kernel(
    const __bf16* __restrict__ Qb, const __bf16* __restrict__ Kb,
    const __bf16* __restrict__ Vt, __bf16* __restrict__ Ob,
    float* __restrict__ attn_out)
{
    const int bh = blockIdx.x;
    const int qb = 63 - blockIdx.y;          // long WGs dispatch first

    const int w    = threadIdx.x >> 6;
    const int lane = threadIdx.x & 63;
    const int l15  = lane & 15;
    const int lg   = lane >> 4;

    const __bf16* Qh = Qb + (size_t)bh * LL * HD;
    const __bf16* Kh = Kb + (size_t)bh * LL * HD;
    const __bf16* Vh = Vt + (size_t)bh * HD * LL;
    float* A_out = attn_out + (size_t)bh * LL * LL;

    __shared__ __bf16 P[4][16][72];          // wave-private 16x64 (+8 pad)

    const int q0 = qb * 64 + w * 16;         // this wave's q-row base
    const bf16x8 qf0 = *reinterpret_cast<const bf16x8*>(&Qh[(size_t)(q0 + l15) * HD + lg * 8]);
    const bf16x8 qf1 = *reinterpret_cast<const bf16x8*>(&Qh[(size_t)(q0 + l15) * HD + 32 + lg * 8]);

    const float SC = 0.125f * 1.44269504088896f;   // scale * log2(e)

    // ---------------- pass 1: row sums ----------------
    float rs[4] = {0.f, 0.f, 0.f, 0.f};
    for (int kb = 0; kb <= qb; ++kb) {
        f32x4 s[4] = {};
#pragma unroll
        for (int kt = 0; kt < 4; ++kt) {
            const __bf16* kp = &Kh[(size_t)(kb * 64 + kt * 16 + l15) * HD + lg * 8];
            const bf16x8 k0 = *reinterpret_cast<const bf16x8*>(kp);
            const bf16x8 k1 = *reinterpret_cast<const bf16x8*>(kp + 32);
            s[kt] = __builtin_amdgcn_mfma_f32_16x16x32_bf16(qf0, k0, s[kt], 0, 0, 0);
            s[kt] = __builtin_amdgcn_mfma_f32_16x16x32_bf16(qf1, k1, s[kt], 0, 0, 0);
        }
        if (kb == qb) {
#pragma unroll
            for (int kt = 0; kt < 4; ++kt)
#pragma unroll
                for (int i = 0; i < 4; ++i) {
                    const int kcol = kb * 64 + kt * 16 + l15;
                    const int qrow = q0 + lg * 4 + i;
                    rs[i] += (kcol <= qrow) ? exp2f(s[kt][i] * SC) : 0.f;
                }
        } else {
#pragma unroll
            for (int kt = 0; kt < 4; ++kt)
#pragma unroll
                for (int i = 0; i < 4; ++i)
                    rs[i] += exp2f(s[kt][i] * SC);
        }
    }
#pragma unroll
    for (int off = 1; off < 16; off <<= 1)
#pragma unroll
        for (int i = 0; i < 4; ++i)
            rs[i] += __shfl_xor(rs[i], off, 64);
    float llog[4];
#pragma unroll
    for (int i = 0; i < 4; ++i) llog[i] = -log2f(rs[i]);

    // ---------------- pass 2 ----------------
    f32x4 oacc[4] = {};
    const int arow = lane >> 2;              // 0..15
    const int aseg = lane & 3;

    for (int kb = 0; kb <= qb; ++kb) {
        f32x4 s[4] = {};
#pragma unroll
        for (int kt = 0; kt < 4; ++kt) {
            const __bf16* kp = &Kh[(size_t)(kb * 64 + kt * 16 + l15) * HD + lg * 8];
            const bf16x8 k0 = *reinterpret_cast<const bf16x8*>(kp);
            const bf16x8 k1 = *reinterpret_cast<const bf16x8*>(kp + 32);
            s[kt] = __builtin_amdgcn_mfma_f32_16x16x32_bf16(qf0, k0, s[kt], 0, 0, 0);
            s[kt] = __builtin_amdgcn_mfma_f32_16x16x32_bf16(qf1, k1, s[kt], 0, 0, 0);
        }
        // normalized P -> wave-private LDS (bf16)
        if (kb == qb) {
#pragma unroll
            for (int kt = 0; kt < 4; ++kt)
#pragma unroll
                for (int i = 0; i < 4; ++i) {
                    const int kcol = kb * 64 + kt * 16 + l15;
                    const int qrow = q0 + lg * 4 + i;
                    float e = exp2f(fmaf(s[kt][i], SC, llog[i]));
                    if (kcol > qrow) e = 0.f;
                    P[w][lg * 4 + i][kt * 16 + l15] = (__bf16)e;
                }
        } else {
#pragma unroll
            for (int kt = 0; kt < 4; ++kt)
#pragma unroll
                for (int i = 0; i < 4; ++i)
                    P[w][lg * 4 + i][kt * 16 + l15] =
                        (__bf16)exp2f(fmaf(s[kt][i], SC, llog[i]));
        }

        // attn write: 16 consecutive fp32 per lane (4x dwordx4), from bf16 LDS
        {
            uint4 a0 = *reinterpret_cast<const uint4*>(&P[w][arow][aseg * 16]);
            uint4 a1 = *reinterpret_cast<const uint4*>(&P[w][arow][aseg * 16 + 8]);
            float4* dst = reinterpret_cast<float4*>(
                &A_out[(size_t)(q0 + arow) * LL + kb * 64 + aseg * 16]);
            dst[0] = up4(a0.x, a0.y);
            dst[1] = up4(a0.z, a0.w);
            dst[2] = up4(a1.x, a1.y);
            dst[3] = up4(a1.z, a1.w);
        }

        // PV: O[q][hd] += P[q][k] V[k][hd]
        const bf16x8 pa0 = *reinterpret_cast<const bf16x8*>(&P[w][l15][lg * 8]);
        const bf16x8 pa1 = *reinterpret_cast<const bf16x8*>(&P[w][l15][32 + lg * 8]);
#pragma unroll
        for (int ht = 0; ht < 4; ++ht) {
            const __bf16* vp = &Vh[(size_t)(ht * 16 + l15) * LL + kb * 64 + lg * 8];
            const bf16x8 vf0 = *reinterpret_cast<const bf16x8*>(vp);
            const bf16x8 vf1 = *reinterpret_cast<const bf16x8*>(vp + 32);
            oacc[ht] = __builtin_amdgcn_mfma_f32_16x16x32_bf16(pa0, vf0, oacc[ht], 0, 0, 0);
            oacc[ht] = __builtin_amdgcn_mfma_f32_16x16x32_bf16(pa1, vf1, oacc[ht], 0, 0, 0);
        }
    }

    // O tile -> LDS (reuse P[w]) -> coalesced bf16 write
    {
#pragma unroll
        for (int ht = 0; ht < 4; ++ht)
#pragma unroll
            for (int i = 0; i < 4; ++i)
                P[w][lg * 4 + i][ht * 16 + l15] = (__bf16)oacc[ht][i];
        uint4 o0 = *reinterpret_cast<const uint4*>(&P[w][arow][aseg * 16]);
        uint4 o1 = *reinterpret_cast<const uint4*>(&P[w][arow][aseg * 16 + 8]);
        const int b = bh >> 3, h = bh & 7;
        __bf16* dst = Ob + ((size_t)(b * LL + q0 + arow)) * DD + h * HD + aseg * 16;
        *reinterpret_cast<uint4*>(dst)     = o0;
        *reinterpret_cast<uint4*>(dst + 8) = o1;
    }

    // zero-fill masked region k >= (qb+1)*64
    {
        const int ztr = threadIdx.x >> 2;            // 0..63
        const int zc  = (threadIdx.x & 3) * 16;
        const size_t rowbase = (size_t)(qb * 64 + ztr) * LL;
        const float4 z4 = {0.f, 0.f, 0.f, 0.f};
        for (int c = (qb + 1) * 64 + zc; c < LL; c += 64) {
            float4* d = reinterpret_cast<float4*>(&A_out[rowbase + c]);
            d[0] = z4; d[1] = z4; d[2] = z4; d[3] = z4;
        }
    }
}

// ---------------------------------------------------------------------------
// Kernel 3: out = Ob(bf16) @ Wo.T + bo -> fp32. grid (BL/64, 8), block 256.
// ---------------------------------------------------------------------------
__global__ __launch_bounds__(256) void oproj_kernel(
    const __bf16* __restrict__ Ob, const float* __restrict__ Wo,
    const float* __restrict__ bo, float* __restrict__ out)
{
    const int wid = threadIdx.x >> 6;
    const int lane = threadIdx.x & 63;
    const int l15 = lane & 15;
    const int lg  = lane >> 4;

    const int r0 = blockIdx.x * 64;
    const int c0 = blockIdx.y * 64 + wid * 16;

    f32x4 acc[4] = {};
    for (int k0 = 0; k0 < DD; k0 += 32) {
        bf16x8 bfrag = cvt8(&Wo[(size_t)(c0 + l15) * DD + k0 + lg * 8]);
#pragma unroll
        for (int mt = 0; mt < 4; ++mt) {
            bf16x8 afrag = *reinterpret_cast<const bf16x8*>(
                &Ob[(size_t)(r0 + mt * 16 + l15) * DD + k0 + lg * 8]);
            acc[mt] = __builtin_amdgcn_mfma_f32_16x16x32_bf16(afrag, bfrag, acc[mt], 0, 0, 0);
        }
    }
    const float bval = bo[c0 + l15];
#pragma unroll
    for (int mt = 0; mt < 4; ++mt)
#pragma unroll
        for (int i = 0; i < 4; ++i)
            out[(size_t)(r0 + mt * 16 + lg * 4 + i) * DD + c0 + l15] = acc[mt][i] + bval;
}

// ---------------------------------------------------------------------------
extern "C" void kernel_launch(void* const* d_in, const int* in_sizes, int n_in,
                              void* d_out, int out_size, void* d_ws, size_t ws_size,
                              hipStream_t stream) {
    const float* query = (const float*)d_in[0];
    const float* key_t = (const float*)d_in[1];
    const float* value = (const float*)d_in[2];
    const float* Wq = (const float*)d_in[3];
    const float* bq = (const float*)d_in[4];
    const float* Wk = (const float*)d_in[5];
    const float* bk = (const float*)d_in[6];
    const float* Wv = (const float*)d_in[7];
    const float* bv = (const float*)d_in[8];
    const float* Wo = (const float*)d_in[9];
    const float* bo = (const float*)d_in[10];

    float* out  = (float*)d_out;             // [B,L,D]
    float* attn = out + OUT_ELEMS;           // [B,H,L,L]

    char* ws = (char*)d_ws;
    __bf16* Qb = (__bf16*)(ws);
    __bf16* Kb = (__bf16*)(ws + (size_t)8 * 1024 * 1024);
    __bf16* Vt = (__bf16*)(ws + (size_t)16 * 1024 * 1024);
    __bf16* Ob = (__bf16*)(ws + (size_t)24 * 1024 * 1024);

    qkv_kernel<<<dim3(BL / 64, DD / 64, 3), 256, 0, stream>>>(
        query, key_t, value, Wq, bq, Wk, bk, Wv, bv, Qb, Kb, Vt);
    attn_kernel<<<dim3(BB * HH, LL / 64), 256, 0, stream>>>(Qb, Kb, Vt, Ob, attn);
    oproj_kernel<<<dim3(BL / 64, DD / 64), 256, 0, stream>>>(Ob, Wo, bo, out);
}

// Round 3
// 854.037 us; speedup vs baseline: 1.0554x; 1.0554x over previous
//
#include <hip/hip_runtime.h>
#include <hip/hip_bf16.h>

// B=2, L=4096, D=512, H=8, Hd=64, causal MHA, outputs (out, attn) fp32.

typedef __attribute__((ext_vector_type(8))) __bf16 bf16x8;
typedef __attribute__((ext_vector_type(4))) __bf16 bf16v4;
typedef __attribute__((ext_vector_type(4))) float f32x4;

constexpr int LL = 4096;
constexpr int DD = 512;
constexpr int HH = 8;
constexpr int HD = 64;
constexpr int BB = 2;
constexpr int BL = BB * LL;
constexpr size_t OUT_ELEMS = (size_t)BB * LL * DD;

static __device__ inline bf16x8 cvt8(const float* p) {
    float4 a = *reinterpret_cast<const float4*>(p);
    float4 b = *reinterpret_cast<const float4*>(p + 4);
    bf16x8 r;
    r[0] = (__bf16)a.x; r[1] = (__bf16)a.y; r[2] = (__bf16)a.z; r[3] = (__bf16)a.w;
    r[4] = (__bf16)b.x; r[5] = (__bf16)b.y; r[6] = (__bf16)b.z; r[7] = (__bf16)b.w;
    return r;
}

static __device__ inline float4 up4(unsigned a, unsigned b) {
    float4 r;
    r.x = __uint_as_float(a << 16);
    r.y = __uint_as_float(a & 0xffff0000u);
    r.z = __uint_as_float(b << 16);
    r.w = __uint_as_float(b & 0xffff0000u);
    return r;
}

// ---------------------------------------------------------------------------
// Kernel 0: fp32 -> bf16 prepack of the three inputs (streaming).
// ---------------------------------------------------------------------------
__global__ __launch_bounds__(256) void cvt_kernel(
    const float* __restrict__ q, const float* __restrict__ k,
    const float* __restrict__ v, __bf16* __restrict__ o)
{
    constexpr size_t N = (size_t)BL * DD;
    size_t i = ((size_t)blockIdx.x * 256 + threadIdx.x) * 8;
    const float* src = q; size_t j = i;
    if (i >= 2 * N)      { src = v; j = i - 2 * N; }
    else if (i >= N)     { src = k; j = i - N; }
    *reinterpret_cast<bf16x8*>(&o[i]) = cvt8(&src[j]);
}

// ---------------------------------------------------------------------------
// Kernel 1: QKV projection from bf16 inputs. y = x @ W.T + b, bf16 out.
// z=0 -> Q [B,H,L,64]; z=1 -> K [B,H,L,64]; z=2 -> V^T [B,H,64,L].
// grid (BL/64, 8, 3), block 256.
// ---------------------------------------------------------------------------
__global__ __launch_bounds__(256) void qkv_kernel(
    const __bf16* __restrict__ Xb,
    const float* __restrict__ Wq, const float* __restrict__ bq,
    const float* __restrict__ Wk, const float* __restrict__ bk,
    const float* __restrict__ Wv, const float* __restrict__ bv,
    __bf16* __restrict__ Qb, __bf16* __restrict__ Kb, __bf16* __restrict__ Vt)
{
    const int z = blockIdx.z;
    const __bf16* x  = Xb + (size_t)z * BL * DD;
    const float* W   = (z == 0) ? Wq : (z == 1) ? Wk : Wv;
    const float* bia = (z == 0) ? bq : (z == 1) ? bk : bv;

    const int wid = threadIdx.x >> 6;
    const int lane = threadIdx.x & 63;
    const int l15 = lane & 15;
    const int lg  = lane >> 4;

    const int r0 = blockIdx.x * 64;
    const int cb = blockIdx.y;
    const int c0 = cb * 64 + wid * 16;

    f32x4 acc[4] = {};
    for (int k0 = 0; k0 < DD; k0 += 32) {
        bf16x8 bfrag = cvt8(&W[(size_t)(c0 + l15) * DD + k0 + lg * 8]);
#pragma unroll
        for (int mt = 0; mt < 4; ++mt) {
            bf16x8 afrag = *reinterpret_cast<const bf16x8*>(
                &x[(size_t)(r0 + mt * 16 + l15) * DD + k0 + lg * 8]);
            acc[mt] = __builtin_amdgcn_mfma_f32_16x16x32_bf16(afrag, bfrag, acc[mt], 0, 0, 0);
        }
    }

    __shared__ __bf16 T[64][72];
    const float bval = bia[c0 + l15];
#pragma unroll
    for (int mt = 0; mt < 4; ++mt)
#pragma unroll
        for (int i = 0; i < 4; ++i) {
            const float val = acc[mt][i] + bval;
            const int row = mt * 16 + lg * 4 + i;
            const int col = wid * 16 + l15;
            if (z == 2) T[col][row] = (__bf16)val;
            else        T[row][col] = (__bf16)val;
        }
    __syncthreads();

    const int tr  = threadIdx.x >> 2;
    const int seg = threadIdx.x & 3;
    uint4 v0 = *reinterpret_cast<const uint4*>(&T[tr][seg * 16]);
    uint4 v1 = *reinterpret_cast<const uint4*>(&T[tr][seg * 16 + 8]);
    const int b  = r0 >> 12;
    const int l0 = r0 & (LL - 1);
    if (z == 2) {
        __bf16* dst = Vt + ((size_t)(b * HH + cb) * HD + tr) * LL + l0 + seg * 16;
        *reinterpret_cast<uint4*>(dst)     = v0;
        *reinterpret_cast<uint4*>(dst + 8) = v1;
    } else {
        __bf16* base = (z == 0) ? Qb : Kb;
        __bf16* dst = base + ((size_t)(b * HH + cb) * LL + l0 + tr) * HD + seg * 16;
        *reinterpret_cast<uint4*>(dst)     = v0;
        *reinterpret_cast<uint4*>(dst + 8) = v1;
    }
}

// ---------------------------------------------------------------------------
// Kernel 2: causal attention. 8 waves/WG: wave w -> rows (w&3)*16, K-parity w>>2.
// Swapped QK^T (mfma(K,Q)) so P is lane-local along k for q = lane&15:
// packed b64 P-stores, scalar llog, 2-step rowsum shuffle.
// Register double-buffered K prefetch; V issued at tile top.
// grid (16 bh, 64 qb-desc), block 512.
// ---------------------------------------------------------------------------
__global__ __launch_bounds__(512, 3) void attn_kernel(
    const __bf16* __restrict__ Qb, const __bf16* __restrict__ Kb,
    const __bf16* __restrict__ Vt, __bf16* __restrict__ Ob,
    float* __restrict__ attn_out)
{
    const int bh = blockIdx.x;
    const int qb = 63 - blockIdx.y;

    const int wv   = threadIdx.x >> 6;   // 0..7
    const int wr   = wv & 3;             // row quarter
    const int par  = wv >> 2;            // K parity
    const int lane = threadIdx.x & 63;
    const int l15  = lane & 15;
    const int lg   = lane >> 4;

    const __bf16* Qh = Qb + (size_t)bh * LL * HD;
    const __bf16* Kh = Kb + (size_t)bh * LL * HD;
    const __bf16* Vh = Vt + (size_t)bh * HD * LL;
    float* A_out = attn_out + (size_t)bh * LL * LL;

    __shared__ __bf16 P[8][16][72];
    __shared__ float rsum[2][64];

    const int q0 = qb * 64 + wr * 16;
    const int qrow = q0 + l15;
    const bf16x8 qf0 = *reinterpret_cast<const bf16x8*>(&Qh[(size_t)(q0 + l15) * HD + lg * 8]);
    const bf16x8 qf1 = *reinterpret_cast<const bf16x8*>(&Qh[(size_t)(q0 + l15) * HD + 32 + lg * 8]);

    const float SC = 0.125f * 1.44269504088896f;  // scale * log2(e)

    auto loadK = [&](bf16x8 (&kf)[8], int kb) {
        const __bf16* kp = &Kh[((size_t)kb * 64 + l15) * HD + lg * 8];
#pragma unroll
        for (int kt = 0; kt < 4; ++kt) {
            kf[kt * 2]     = *reinterpret_cast<const bf16x8*>(kp + (size_t)kt * 16 * HD);
            kf[kt * 2 + 1] = *reinterpret_cast<const bf16x8*>(kp + (size_t)kt * 16 * HD + 32);
        }
    };

    // ---------------- pass 1: row sums over this parity's tiles ----------------
    float rs = 0.f;
    auto body1 = [&](bf16x8 (&kf)[8], int kb) {
        f32x4 s[4] = {};
#pragma unroll
        for (int kt = 0; kt < 4; ++kt) {
            s[kt] = __builtin_amdgcn_mfma_f32_16x16x32_bf16(kf[kt * 2],     qf0, s[kt], 0, 0, 0);
            s[kt] = __builtin_amdgcn_mfma_f32_16x16x32_bf16(kf[kt * 2 + 1], qf1, s[kt], 0, 0, 0);
        }
        const bool diag = (kb == qb);
#pragma unroll
        for (int kt = 0; kt < 4; ++kt)
#pragma unroll
            for (int i = 0; i < 4; ++i) {
                float e = exp2f(s[kt][i] * SC);
                if (diag && (kb * 64 + kt * 16 + lg * 4 + i) > qrow) e = 0.f;
                rs += e;
            }
    };
    {
        bf16x8 kA[8], kB[8];
        int kb = par;
        bool useA = true;
        if (kb <= qb) loadK(kA, kb);
        for (; kb <= qb; kb += 2) {
            if (useA) { if (kb + 2 <= qb) loadK(kB, kb + 2); body1(kA, kb); }
            else      { if (kb + 2 <= qb) loadK(kA, kb + 2); body1(kB, kb); }
            useA = !useA;
        }
    }
    rs += __shfl_xor(rs, 16, 64);
    rs += __shfl_xor(rs, 32, 64);
    if (lane < 16) rsum[par][wr * 16 + l15] = rs;
    __syncthreads();
    const float llog = -log2f(rsum[0][wr * 16 + l15] + rsum[1][wr * 16 + l15]);

    // ---------------- pass 2: attn write + PV ----------------
    f32x4 oacc[4] = {};
    const int arow = lane >> 2;
    const int aseg = lane & 3;

    auto body2 = [&](bf16x8 (&kf)[8], int kb) {
        // V loads issue first; consumed after the P chain (~400cy of cover)
        bf16x8 vf[8];
        {
            const __bf16* vp = &Vh[(size_t)l15 * LL + (size_t)kb * 64 + lg * 8];
#pragma unroll
            for (int ht = 0; ht < 4; ++ht) {
                vf[ht * 2]     = *reinterpret_cast<const bf16x8*>(vp + (size_t)ht * 16 * LL);
                vf[ht * 2 + 1] = *reinterpret_cast<const bf16x8*>(vp + (size_t)ht * 16 * LL + 32);
            }
        }
        f32x4 s[4] = {};
#pragma unroll
        for (int kt = 0; kt < 4; ++kt) {
            s[kt] = __builtin_amdgcn_mfma_f32_16x16x32_bf16(kf[kt * 2],     qf0, s[kt], 0, 0, 0);
            s[kt] = __builtin_amdgcn_mfma_f32_16x16x32_bf16(kf[kt * 2 + 1], qf1, s[kt], 0, 0, 0);
        }
        const bool diag = (kb == qb);
#pragma unroll
        for (int kt = 0; kt < 4; ++kt) {
            bf16v4 pk;
#pragma unroll
            for (int i = 0; i < 4; ++i) {
                float e = exp2f(fmaf(s[kt][i], SC, llog));
                if (diag && (kb * 64 + kt * 16 + lg * 4 + i) > qrow) e = 0.f;
                pk[i] = (__bf16)e;
            }
            *reinterpret_cast<bf16v4*>(&P[wv][l15][kt * 16 + lg * 4]) = pk;  // ds_write_b64
        }
        // attn write: 16 consecutive fp32 per lane from own wave's P tile
        {
            uint4 a0 = *reinterpret_cast<const uint4*>(&P[wv][arow][aseg * 16]);
            uint4 a1 = *reinterpret_cast<const uint4*>(&P[wv][arow][aseg * 16 + 8]);
            float4* dst = reinterpret_cast<float4*>(
                &A_out[(size_t)(q0 + arow) * LL + kb * 64 + aseg * 16]);
            dst[0] = up4(a0.x, a0.y);
            dst[1] = up4(a0.z, a0.w);
            dst[2] = up4(a1.x, a1.y);
            dst[3] = up4(a1.z, a1.w);
        }
        // PV
        const bf16x8 pa0 = *reinterpret_cast<const bf16x8*>(&P[wv][l15][lg * 8]);
        const bf16x8 pa1 = *reinterpret_cast<const bf16x8*>(&P[wv][l15][32 + lg * 8]);
#pragma unroll
        for (int ht = 0; ht < 4; ++ht) {
            oacc[ht] = __builtin_amdgcn_mfma_f32_16x16x32_bf16(pa0, vf[ht * 2],     oacc[ht], 0, 0, 0);
            oacc[ht] = __builtin_amdgcn_mfma_f32_16x16x32_bf16(pa1, vf[ht * 2 + 1], oacc[ht], 0, 0, 0);
        }
    };
    {
        bf16x8 kA[8], kB[8];
        int kb = par;
        bool useA = true;
        if (kb <= qb) loadK(kA, kb);
        for (; kb <= qb; kb += 2) {
            if (useA) { if (kb + 2 <= qb) loadK(kB, kb + 2); body2(kA, kb); }
            else      { if (kb + 2 <= qb) loadK(kA, kb + 2); body2(kB, kb); }
            useA = !useA;
        }
    }

    // combine O across parities, write Ob (bf16 partial round is well in tolerance)
    if (par == 1) {
#pragma unroll
        for (int ht = 0; ht < 4; ++ht)
#pragma unroll
            for (int i = 0; i < 4; ++i)
                P[wv][lg * 4 + i][ht * 16 + l15] = (__bf16)oacc[ht][i];
    }
    __syncthreads();
    if (par == 0) {
#pragma unroll
        for (int ht = 0; ht < 4; ++ht)
#pragma unroll
            for (int i = 0; i < 4; ++i)
                oacc[ht][i] += (float)P[wv + 4][lg * 4 + i][ht * 16 + l15];
#pragma unroll
        for (int ht = 0; ht < 4; ++ht)
#pragma unroll
            for (int i = 0; i < 4; ++i)
                P[wv][lg * 4 + i][ht * 16 + l15] = (__bf16)oacc[ht][i];
        uint4 o0 = *reinterpret_cast<const uint4*>(&P[wv][arow][aseg * 16]);
        uint4 o1 = *reinterpret_cast<const uint4*>(&P[wv][arow][aseg * 16 + 8]);
        const int b = bh >> 3, h = bh & 7;
        __bf16* dst = Ob + ((size_t)(b * LL + q0 + arow)) * DD + h * HD + aseg * 16;
        *reinterpret_cast<uint4*>(dst)     = o0;
        *reinterpret_cast<uint4*>(dst + 8) = o1;
    }

    // zero-fill masked region, all 512 threads
    {
        const int ztr  = threadIdx.x >> 3;       // 0..63
        const int zseg = threadIdx.x & 7;        // 8 x 16 floats = 128/iter
        const size_t rowbase = (size_t)(qb * 64 + ztr) * LL;
        const float4 z4 = {0.f, 0.f, 0.f, 0.f};
        for (int c = (qb + 1) * 64 + zseg * 16; c < LL; c += 128) {
            float4* d = reinterpret_cast<float4*>(&A_out[rowbase + c]);
            d[0] = z4; d[1] = z4; d[2] = z4; d[3] = z4;
        }
    }
}

// ---------------------------------------------------------------------------
// Kernel 3: out = Ob(bf16) @ Wo.T + bo -> fp32. grid (BL/64, 8), block 256.
// ---------------------------------------------------------------------------
__global__ __launch_bounds__(256) void oproj_kernel(
    const __bf16* __restrict__ Ob, const float* __restrict__ Wo,
    const float* __restrict__ bo, float* __restrict__ out)
{
    const int wid = threadIdx.x >> 6;
    const int lane = threadIdx.x & 63;
    const int l15 = lane & 15;
    const int lg  = lane >> 4;

    const int r0 = blockIdx.x * 64;
    const int c0 = blockIdx.y * 64 + wid * 16;

    f32x4 acc[4] = {};
    for (int k0 = 0; k0 < DD; k0 += 32) {
        bf16x8 bfrag = cvt8(&Wo[(size_t)(c0 + l15) * DD + k0 + lg * 8]);
#pragma unroll
        for (int mt = 0; mt < 4; ++mt) {
            bf16x8 afrag = *reinterpret_cast<const bf16x8*>(
                &Ob[(size_t)(r0 + mt * 16 + l15) * DD + k0 + lg * 8]);
            acc[mt] = __builtin_amdgcn_mfma_f32_16x16x32_bf16(afrag, bfrag, acc[mt], 0, 0, 0);
        }
    }
    const float bval = bo[c0 + l15];
#pragma unroll
    for (int mt = 0; mt < 4; ++mt)
#pragma unroll
        for (int i = 0; i < 4; ++i)
            out[(size_t)(r0 + mt * 16 + lg * 4 + i) * DD + c0 + l15] = acc[mt][i] + bval;
}

// ---------------------------------------------------------------------------
extern "C" void kernel_launch(void* const* d_in, const int* in_sizes, int n_in,
                              void* d_out, int out_size, void* d_ws, size_t ws_size,
                              hipStream_t stream) {
    const float* query = (const float*)d_in[0];
    const float* key_t = (const float*)d_in[1];
    const float* value = (const float*)d_in[2];
    const float* Wq = (const float*)d_in[3];
    const float* bq = (const float*)d_in[4];
    const float* Wk = (const float*)d_in[5];
    const float* bk = (const float*)d_in[6];
    const float* Wv = (const float*)d_in[7];
    const float* bv = (const float*)d_in[8];
    const float* Wo = (const float*)d_in[9];
    const float* bo = (const float*)d_in[10];

    float* out  = (float*)d_out;             // [B,L,D]
    float* attn = out + OUT_ELEMS;           // [B,H,L,L]

    char* ws = (char*)d_ws;
    __bf16* Qb = (__bf16*)(ws);
    __bf16* Kb = (__bf16*)(ws + (size_t)8 * 1024 * 1024);
    __bf16* Vt = (__bf16*)(ws + (size_t)16 * 1024 * 1024);
    __bf16* Ob = (__bf16*)(ws + (size_t)24 * 1024 * 1024);
    __bf16* Xb = (__bf16*)(ws + (size_t)32 * 1024 * 1024);   // 24 MiB

    cvt_kernel<<<dim3(3 * BL * DD / 8 / 256), 256, 0, stream>>>(query, key_t, value, Xb);
    qkv_kernel<<<dim3(BL / 64, DD / 64, 3), 256, 0, stream>>>(
        Xb, Wq, bq, Wk, bk, Wv, bv, Qb, Kb, Vt);
    attn_kernel<<<dim3(BB * HH, LL / 64), 512, 0, stream>>>(Qb, Kb, Vt, Ob, attn);
    oproj_kernel<<<dim3(BL / 64, DD / 64), 256, 0, stream>>>(Ob, Wo, bo, out);
}

// Round 4
// 786.847 us; speedup vs baseline: 1.1455x; 1.0854x over previous
//
#include <hip/hip_runtime.h>
#include <hip/hip_bf16.h>

// B=2, L=4096, D=512, H=8, Hd=64, causal MHA, outputs (out, attn) fp32.

typedef __attribute__((ext_vector_type(8))) __bf16 bf16x8;
typedef __attribute__((ext_vector_type(4))) __bf16 bf16v4;
typedef __attribute__((ext_vector_type(4))) float f32x4;

constexpr int LL = 4096;
constexpr int DD = 512;
constexpr int HH = 8;
constexpr int HD = 64;
constexpr int BB = 2;
constexpr int BL = BB * LL;
constexpr size_t OUT_ELEMS = (size_t)BB * LL * DD;
constexpr int CH = 16;                  // 64-col K-tiles per chunk (1024 cols)
constexpr int NCHUNK = LL / 64 / CH;    // 4

static __device__ inline bf16x8 cvt8(const float* p) {
    float4 a = *reinterpret_cast<const float4*>(p);
    float4 b = *reinterpret_cast<const float4*>(p + 4);
    bf16x8 r;
    r[0] = (__bf16)a.x; r[1] = (__bf16)a.y; r[2] = (__bf16)a.z; r[3] = (__bf16)a.w;
    r[4] = (__bf16)b.x; r[5] = (__bf16)b.y; r[6] = (__bf16)b.z; r[7] = (__bf16)b.w;
    return r;
}

// ---------------------------------------------------------------------------
// Kernel 0: fp32 -> bf16 prepack of the three inputs.
// ---------------------------------------------------------------------------
__global__ __launch_bounds__(256) void cvt_kernel(
    const float* __restrict__ q, const float* __restrict__ k,
    const float* __restrict__ v, __bf16* __restrict__ o)
{
    constexpr size_t N = (size_t)BL * DD;
    size_t i = ((size_t)blockIdx.x * 256 + threadIdx.x) * 8;
    const float* src = q; size_t j = i;
    if (i >= 2 * N)      { src = v; j = i - 2 * N; }
    else if (i >= N)     { src = k; j = i - N; }
    *reinterpret_cast<bf16x8*>(&o[i]) = cvt8(&src[j]);
}

// ---------------------------------------------------------------------------
// Kernel 1: QKV projection from bf16 inputs. y = x @ W.T + b, bf16 out.
// z=0 -> Q [B,H,L,64]; z=1 -> K [B,H,L,64]; z=2 -> V^T [B,H,64,L].
// grid (BL/64, 8, 3), block 256.
// ---------------------------------------------------------------------------
__global__ __launch_bounds__(256) void qkv_kernel(
    const __bf16* __restrict__ Xb,
    const float* __restrict__ Wq, const float* __restrict__ bq,
    const float* __restrict__ Wk, const float* __restrict__ bk,
    const float* __restrict__ Wv, const float* __restrict__ bv,
    __bf16* __restrict__ Qb, __bf16* __restrict__ Kb, __bf16* __restrict__ Vt)
{
    const int z = blockIdx.z;
    const __bf16* x  = Xb + (size_t)z * BL * DD;
    const float* W   = (z == 0) ? Wq : (z == 1) ? Wk : Wv;
    const float* bia = (z == 0) ? bq : (z == 1) ? bk : bv;

    const int wid = threadIdx.x >> 6;
    const int lane = threadIdx.x & 63;
    const int l15 = lane & 15;
    const int lg  = lane >> 4;

    const int r0 = blockIdx.x * 64;
    const int cb = blockIdx.y;
    const int c0 = cb * 64 + wid * 16;

    f32x4 acc[4] = {};
    for (int k0 = 0; k0 < DD; k0 += 32) {
        bf16x8 bfrag = cvt8(&W[(size_t)(c0 + l15) * DD + k0 + lg * 8]);
#pragma unroll
        for (int mt = 0; mt < 4; ++mt) {
            bf16x8 afrag = *reinterpret_cast<const bf16x8*>(
                &x[(size_t)(r0 + mt * 16 + l15) * DD + k0 + lg * 8]);
            acc[mt] = __builtin_amdgcn_mfma_f32_16x16x32_bf16(afrag, bfrag, acc[mt], 0, 0, 0);
        }
    }

    __shared__ __bf16 T[64][72];
    const float bval = bia[c0 + l15];
#pragma unroll
    for (int mt = 0; mt < 4; ++mt)
#pragma unroll
        for (int i = 0; i < 4; ++i) {
            const float val = acc[mt][i] + bval;
            const int row = mt * 16 + lg * 4 + i;
            const int col = wid * 16 + l15;
            if (z == 2) T[col][row] = (__bf16)val;
            else        T[row][col] = (__bf16)val;
        }
    __syncthreads();

    const int tr  = threadIdx.x >> 2;
    const int seg = threadIdx.x & 3;
    uint4 v0 = *reinterpret_cast<const uint4*>(&T[tr][seg * 16]);
    uint4 v1 = *reinterpret_cast<const uint4*>(&T[tr][seg * 16 + 8]);
    const int b  = r0 >> 12;
    const int l0 = r0 & (LL - 1);
    if (z == 2) {
        __bf16* dst = Vt + ((size_t)(b * HH + cb) * HD + tr) * LL + l0 + seg * 16;
        *reinterpret_cast<uint4*>(dst)     = v0;
        *reinterpret_cast<uint4*>(dst + 8) = v1;
    } else {
        __bf16* base = (z == 0) ? Qb : Kb;
        __bf16* dst = base + ((size_t)(b * HH + cb) * LL + l0 + tr) * HD + seg * 16;
        *reinterpret_cast<uint4*>(dst)     = v0;
        *reinterpret_cast<uint4*>(dst + 8) = v1;
    }
}

// ---------------------------------------------------------------------------
// Kernel 2a: chunked row sums. WG (bh, qb, ch) sums exp(s) over its <=16
// K-tiles, writes rspart[bh][qrow][ch]. Swapped QK (mfma(K,Q)): q = lane&15.
// grid (16, 64, 4), block 256; WGs fully above diag exit.
// ---------------------------------------------------------------------------
__global__ __launch_bounds__(256) void rowsum_kernel(
    const __bf16* __restrict__ Qb, const __bf16* __restrict__ Kb,
    float* __restrict__ rspart)
{
    const int bh = blockIdx.x;
    const int qb = 63 - blockIdx.y;          // heavy WGs first
    const int ch = blockIdx.z;
    if (ch * CH > qb) return;

    const int wv   = threadIdx.x >> 6;
    const int lane = threadIdx.x & 63;
    const int l15  = lane & 15;
    const int lg   = lane >> 4;

    const __bf16* Qh = Qb + (size_t)bh * LL * HD;
    const __bf16* Kh = Kb + (size_t)bh * LL * HD;

    const int q0 = qb * 64 + wv * 16;
    const int qrow = q0 + l15;
    const bf16x8 qf0 = *reinterpret_cast<const bf16x8*>(&Qh[(size_t)qrow * HD + lg * 8]);
    const bf16x8 qf1 = *reinterpret_cast<const bf16x8*>(&Qh[(size_t)qrow * HD + 32 + lg * 8]);
    const float SC = 0.125f * 1.44269504088896f;

    float rs = 0.f;
    const int kend = (qb < ch * CH + CH - 1) ? qb : ch * CH + CH - 1;
    for (int kb = ch * CH; kb <= kend; ++kb) {
        f32x4 s[4] = {};
#pragma unroll
        for (int kt = 0; kt < 4; ++kt) {
            const __bf16* kp = &Kh[(size_t)(kb * 64 + kt * 16 + l15) * HD + lg * 8];
            const bf16x8 k0 = *reinterpret_cast<const bf16x8*>(kp);
            const bf16x8 k1 = *reinterpret_cast<const bf16x8*>(kp + 32);
            s[kt] = __builtin_amdgcn_mfma_f32_16x16x32_bf16(k0, qf0, s[kt], 0, 0, 0);
            s[kt] = __builtin_amdgcn_mfma_f32_16x16x32_bf16(k1, qf1, s[kt], 0, 0, 0);
        }
        const bool diag = (kb == qb);
#pragma unroll
        for (int kt = 0; kt < 4; ++kt)
#pragma unroll
            for (int i = 0; i < 4; ++i) {
                float e = exp2f(s[kt][i] * SC);
                if (diag && (kb * 64 + kt * 16 + lg * 4 + i) > qrow) e = 0.f;
                rs += e;
            }
    }
    rs += __shfl_xor(rs, 16, 64);
    rs += __shfl_xor(rs, 32, 64);
    if (lane < 16)
        rspart[((size_t)bh * LL + qrow) * NCHUNK + ch] = rs;
}

// ---------------------------------------------------------------------------
// Kernel 2b: chunked attn write + partial PV. WG (bh, qb, ch): sums its row's
// rspart -> llog; per K-tile: QK, normalize, DIRECT fp32 attn store from regs,
// P->LDS (wave-private) -> PV accumulate. Above-diag tiles store zeros.
// O-partial (64x64 bf16) per chunk -> opart. grid (16, 64, 4), block 256.
// ---------------------------------------------------------------------------
__global__ __launch_bounds__(256, 4) void attn_main_kernel(
    const __bf16* __restrict__ Qb, const __bf16* __restrict__ Kb,
    const __bf16* __restrict__ Vt, const float* __restrict__ rspart,
    __bf16* __restrict__ opart, float* __restrict__ attn_out)
{
    const int bh = blockIdx.x;
    const int qb = 63 - blockIdx.y;
    const int ch = blockIdx.z;

    const int wv   = threadIdx.x >> 6;
    const int lane = threadIdx.x & 63;
    const int l15  = lane & 15;
    const int lg   = lane >> 4;

    float* A_out = attn_out + (size_t)bh * LL * LL;
    const int q0 = qb * 64 + wv * 16;
    const int qrow = q0 + l15;
    const int kb0 = ch * CH;

    if (kb0 > qb) {
        // whole chunk above diagonal: pure zero-fill
        const float4 z4 = {0.f, 0.f, 0.f, 0.f};
        float4* dst = reinterpret_cast<float4*>(&A_out[(size_t)qrow * LL + kb0 * 64 + lg * 4]);
        for (int t = 0; t < CH; ++t) {
#pragma unroll
            for (int kt = 0; kt < 4; ++kt) dst[kt * 4] = z4;
            dst += 16;                        // 64 floats to next tile
        }
        return;
    }

    const __bf16* Qh = Qb + (size_t)bh * LL * HD;
    const __bf16* Kh = Kb + (size_t)bh * LL * HD;
    const __bf16* Vh = Vt + (size_t)bh * HD * LL;

    __shared__ __bf16 P[4][16][72];           // wave-private P tile

    const bf16x8 qf0 = *reinterpret_cast<const bf16x8*>(&Qh[(size_t)qrow * HD + lg * 8]);
    const bf16x8 qf1 = *reinterpret_cast<const bf16x8*>(&Qh[(size_t)qrow * HD + 32 + lg * 8]);

    // normalization from partial row sums
    float rsv = 0.f;
    const int nc = qb >> 4;
    const float* rp = &rspart[((size_t)bh * LL + qrow) * NCHUNK];
    for (int c = 0; c <= nc; ++c) rsv += rp[c];
    const float llog = -log2f(rsv);
    const float SC = 0.125f * 1.44269504088896f;

    f32x4 oacc[4] = {};

    for (int t = 0; t < CH; ++t) {
        const int kb = kb0 + t;
        if (kb > qb) {                         // above-diag tile: zeros
            const float4 z4 = {0.f, 0.f, 0.f, 0.f};
            float4* dst = reinterpret_cast<float4*>(
                &A_out[(size_t)qrow * LL + kb * 64 + lg * 4]);
#pragma unroll
            for (int kt = 0; kt < 4; ++kt) dst[kt * 4] = z4;
            continue;
        }
        // issue all K and V loads up front (16 outstanding dwordx4)
        bf16x8 kf[8], vf[8];
        {
            const __bf16* kp = &Kh[(size_t)(kb * 64 + l15) * HD + lg * 8];
#pragma unroll
            for (int kt = 0; kt < 4; ++kt) {
                kf[kt * 2]     = *reinterpret_cast<const bf16x8*>(kp + (size_t)kt * 16 * HD);
                kf[kt * 2 + 1] = *reinterpret_cast<const bf16x8*>(kp + (size_t)kt * 16 * HD + 32);
            }
            const __bf16* vp = &Vh[(size_t)l15 * LL + (size_t)kb * 64 + lg * 8];
#pragma unroll
            for (int ht = 0; ht < 4; ++ht) {
                vf[ht * 2]     = *reinterpret_cast<const bf16x8*>(vp + (size_t)ht * 16 * LL);
                vf[ht * 2 + 1] = *reinterpret_cast<const bf16x8*>(vp + (size_t)ht * 16 * LL + 32);
            }
        }
        f32x4 s[4] = {};
#pragma unroll
        for (int kt = 0; kt < 4; ++kt) {
            s[kt] = __builtin_amdgcn_mfma_f32_16x16x32_bf16(kf[kt * 2],     qf0, s[kt], 0, 0, 0);
            s[kt] = __builtin_amdgcn_mfma_f32_16x16x32_bf16(kf[kt * 2 + 1], qf1, s[kt], 0, 0, 0);
        }
        const bool diag = (kb == qb);
#pragma unroll
        for (int kt = 0; kt < 4; ++kt) {
            float e0 = exp2f(fmaf(s[kt][0], SC, llog));
            float e1 = exp2f(fmaf(s[kt][1], SC, llog));
            float e2 = exp2f(fmaf(s[kt][2], SC, llog));
            float e3 = exp2f(fmaf(s[kt][3], SC, llog));
            if (diag) {
                const int kc = kb * 64 + kt * 16 + lg * 4;
                if (kc + 0 > qrow) e0 = 0.f;
                if (kc + 1 > qrow) e1 = 0.f;
                if (kc + 2 > qrow) e2 = 0.f;
                if (kc + 3 > qrow) e3 = 0.f;
            }
            // direct fp32 attn store (16 rows x 64B per instruction)
            float4 ev = {e0, e1, e2, e3};
            *reinterpret_cast<float4*>(
                &A_out[(size_t)qrow * LL + kb * 64 + kt * 16 + lg * 4]) = ev;
            // bf16 pack for PV
            bf16v4 pk;
            pk[0] = (__bf16)e0; pk[1] = (__bf16)e1;
            pk[2] = (__bf16)e2; pk[3] = (__bf16)e3;
            *reinterpret_cast<bf16v4*>(&P[wv][l15][kt * 16 + lg * 4]) = pk;
        }
        // PV (vf arrived during the exp/store phase)
        const bf16x8 pa0 = *reinterpret_cast<const bf16x8*>(&P[wv][l15][lg * 8]);
        const bf16x8 pa1 = *reinterpret_cast<const bf16x8*>(&P[wv][l15][32 + lg * 8]);
#pragma unroll
        for (int ht = 0; ht < 4; ++ht) {
            oacc[ht] = __builtin_amdgcn_mfma_f32_16x16x32_bf16(pa0, vf[ht * 2],     oacc[ht], 0, 0, 0);
            oacc[ht] = __builtin_amdgcn_mfma_f32_16x16x32_bf16(pa1, vf[ht * 2 + 1], oacc[ht], 0, 0, 0);
        }
    }

    // O partial -> LDS (reuse P, wave-private, in-order DS) -> coalesced store
#pragma unroll
    for (int ht = 0; ht < 4; ++ht)
#pragma unroll
        for (int i = 0; i < 4; ++i)
            P[wv][lg * 4 + i][ht * 16 + l15] = (__bf16)oacc[ht][i];
    const int arow = lane >> 2;
    const int aseg = lane & 3;
    uint4 o0 = *reinterpret_cast<const uint4*>(&P[wv][arow][aseg * 16]);
    uint4 o1 = *reinterpret_cast<const uint4*>(&P[wv][arow][aseg * 16 + 8]);
    __bf16* dst = opart + ((size_t)((bh * 64 + qb) * NCHUNK + ch)) * 4096
                + (wv * 16 + arow) * 64 + aseg * 16;
    *reinterpret_cast<uint4*>(dst)     = o0;
    *reinterpret_cast<uint4*>(dst + 8) = o1;
}

// ---------------------------------------------------------------------------
// Kernel 2c: sum O-partials (<=4) -> Ob bf16 [B,L,D]. grid (16, 64), block 256.
// ---------------------------------------------------------------------------
__global__ __launch_bounds__(256) void oreduce_kernel(
    const __bf16* __restrict__ opart, __bf16* __restrict__ Ob)
{
    const int bh = blockIdx.x;
    const int qb = blockIdx.y;
    const int nc = qb >> 4;
    const __bf16* src = opart + ((size_t)(bh * 64 + qb) * NCHUNK) * 4096;
    const int t = threadIdx.x;

    float acc[16] = {};
    for (int c = 0; c <= nc; ++c) {
        bf16x8 a = *reinterpret_cast<const bf16x8*>(&src[(size_t)c * 4096 + t * 16]);
        bf16x8 b = *reinterpret_cast<const bf16x8*>(&src[(size_t)c * 4096 + t * 16 + 8]);
#pragma unroll
        for (int j = 0; j < 8; ++j) { acc[j] += (float)a[j]; acc[8 + j] += (float)b[j]; }
    }
    bf16x8 r0, r1;
#pragma unroll
    for (int j = 0; j < 8; ++j) { r0[j] = (__bf16)acc[j]; r1[j] = (__bf16)acc[8 + j]; }

    const int qr  = t >> 2;
    const int hd0 = (t & 3) * 16;
    const int b = bh >> 3, h = bh & 7;
    __bf16* dst = Ob + ((size_t)(b * LL + qb * 64 + qr)) * DD + h * HD + hd0;
    *reinterpret_cast<bf16x8*>(dst)     = r0;
    *reinterpret_cast<bf16x8*>(dst + 8) = r1;
}

// ---------------------------------------------------------------------------
// Kernel 3: out = Ob(bf16) @ Wo.T + bo -> fp32. grid (BL/64, 8), block 256.
// ---------------------------------------------------------------------------
__global__ __launch_bounds__(256) void oproj_kernel(
    const __bf16* __restrict__ Ob, const float* __restrict__ Wo,
    const float* __restrict__ bo, float* __restrict__ out)
{
    const int wid = threadIdx.x >> 6;
    const int lane = threadIdx.x & 63;
    const int l15 = lane & 15;
    const int lg  = lane >> 4;

    const int r0 = blockIdx.x * 64;
    const int c0 = blockIdx.y * 64 + wid * 16;

    f32x4 acc[4] = {};
    for (int k0 = 0; k0 < DD; k0 += 32) {
        bf16x8 bfrag = cvt8(&Wo[(size_t)(c0 + l15) * DD + k0 + lg * 8]);
#pragma unroll
        for (int mt = 0; mt < 4; ++mt) {
            bf16x8 afrag = *reinterpret_cast<const bf16x8*>(
                &Ob[(size_t)(r0 + mt * 16 + l15) * DD + k0 + lg * 8]);
            acc[mt] = __builtin_amdgcn_mfma_f32_16x16x32_bf16(afrag, bfrag, acc[mt], 0, 0, 0);
        }
    }
    const float bval = bo[c0 + l15];
#pragma unroll
    for (int mt = 0; mt < 4; ++mt)
#pragma unroll
        for (int i = 0; i < 4; ++i)
            out[(size_t)(r0 + mt * 16 + lg * 4 + i) * DD + c0 + l15] = acc[mt][i] + bval;
}

// ---------------------------------------------------------------------------
extern "C" void kernel_launch(void* const* d_in, const int* in_sizes, int n_in,
                              void* d_out, int out_size, void* d_ws, size_t ws_size,
                              hipStream_t stream) {
    const float* query = (const float*)d_in[0];
    const float* key_t = (const float*)d_in[1];
    const float* value = (const float*)d_in[2];
    const float* Wq = (const float*)d_in[3];
    const float* bq = (const float*)d_in[4];
    const float* Wk = (const float*)d_in[5];
    const float* bk = (const float*)d_in[6];
    const float* Wv = (const float*)d_in[7];
    const float* bv = (const float*)d_in[8];
    const float* Wo = (const float*)d_in[9];
    const float* bo = (const float*)d_in[10];

    float* out  = (float*)d_out;             // [B,L,D]
    float* attn = out + OUT_ELEMS;           // [B,H,L,L]

    char* ws = (char*)d_ws;
    __bf16* Qb     = (__bf16*)(ws);                        //  8.39 MB
    __bf16* Kb     = (__bf16*)(ws +  8388608);             //  8.39 MB
    __bf16* Vt     = (__bf16*)(ws + 16777216);             //  8.39 MB
    __bf16* Ob     = (__bf16*)(ws + 25165824);             //  8.39 MB
    float*  rspart = (float*) (ws + 33554432);             //  1.05 MB
    __bf16* Xb     = (__bf16*)(ws + 34603008);             // 25.2 MB (dead after qkv)
    __bf16* opart  = (__bf16*)(ws + 34603008);             // 33.6 MB (overlaps Xb)

    cvt_kernel<<<dim3(3 * BL * DD / 8 / 256), 256, 0, stream>>>(query, key_t, value, Xb);
    qkv_kernel<<<dim3(BL / 64, DD / 64, 3), 256, 0, stream>>>(
        Xb, Wq, bq, Wk, bk, Wv, bv, Qb, Kb, Vt);
    rowsum_kernel<<<dim3(BB * HH, LL / 64, NCHUNK), 256, 0, stream>>>(Qb, Kb, rspart);
    attn_main_kernel<<<dim3(BB * HH, LL / 64, NCHUNK), 256, 0, stream>>>(
        Qb, Kb, Vt, rspart, opart, attn);
    oreduce_kernel<<<dim3(BB * HH, LL / 64), 256, 0, stream>>>(opart, Ob);
    oproj_kernel<<<dim3(BL / 64, DD / 64), 256, 0, stream>>>(Ob, Wo, bo, out);
}